// Round 15
// baseline (348.059 us; speedup 1.0000x reference)
//
#include <hip/hip_runtime.h>
#include <hip/hip_fp16.h>
#include <math.h>

#define N_NODES 100000
#define N_EDGES 1600000
#define IN_DIM 128
#define HEADS 8
#define D1 16
#define D2 8
#define NEG_SLOPE 0.2f

#define NBKT ((N_NODES + 255) / 256)      // 391 buckets of 256 dst nodes
#define PART_CHUNK 4096                   // R16 lesson: bigger chunks -> occupancy collapse
#define BCAP 6144                         // R19: fixed bucket capacity = mean 4096 + 32 sigma
#define BCSTRIDE 32                       // R21: one 128B line per bucket cursor (kept; free)
#define GEMM1_BLOCKS ((N_NODES + 63) / 64)
#define AGG_CHUNK 33334                   // R25: 3-way aggregate split (diagnostic)

typedef _Float16 f16x8 __attribute__((ext_vector_type(8)));
typedef float    f32x4 __attribute__((ext_vector_type(4)));

// 16-byte pack of 8 halves.
struct __align__(16) half8 { __half2 a, b, c, d; };

__device__ __forceinline__ f16x8 load_cvt8(const float* p) {
    float4 v0 = *(const float4*)p, v1 = *(const float4*)(p + 4);
    f16x8 r;
    r[0] = (_Float16)v0.x; r[1] = (_Float16)v0.y;
    r[2] = (_Float16)v0.z; r[3] = (_Float16)v0.w;
    r[4] = (_Float16)v1.x; r[5] = (_Float16)v1.y;
    r[6] = (_Float16)v1.z; r[7] = (_Float16)v1.w;
    return r;
}

// DPP row_shr:N add (VALU only). bound_ctrl=true: OOB reads 0.
// row_shr:N: lane i reads lane i-N — accumulation flows toward HIGHER lanes;
// after shr 8,4,2,1 the 16-lane row sum is in lane 15 (R17 bug: stored from
// lane 0). 8-lane group sums land in lanes 7 and 15.
template<int CTRL>
__device__ __forceinline__ float dpp_add(float x) {
    int y = __builtin_amdgcn_update_dpp(0, __builtin_bit_cast(int, x),
                                        CTRL, 0xF, 0xF, true);
    return x + __builtin_bit_cast(float, y);
}

// ---------------------------------------------------------------------------
// MFMA GEMM body + fused score epilogue (DPP reduce, R18-verified; R22 LDS
// restage for wide coalesced h-stores).
// Fragment pattern (guide m90/m92, HW-verified):
//   A-frag: lane reads A[row0+(lane&15)][ks..ks+8), ks=(lane>>4)*8 per 32-k step
//   B-frag: same from Bt rows (Bt = W^T)
//   C/D  : row=(lane>>4)*4+r, col=j*16+(lane&15)
// Score fusion: col j*16+lr == head*D+d flat for BOTH layers.
// XF32: layer-1 reads x fp32, converts in-register (RN, == old convert_x).
// ---------------------------------------------------------------------------
template<int OUTC, int D, bool XF32>
__device__ __forceinline__ void gemm_body(int gb, const void* __restrict__ Ain,
                                          const __half* __restrict__ Bt,
                                          __half* __restrict__ C,
                                          const float* __restrict__ a_s,
                                          const float* __restrict__ a_d,
                                          float* __restrict__ s_src,
                                          float* __restrict__ s_dst,
                                          int n_rows) {
    constexpr int K = 128;
    constexpr int NT = OUTC / 16;      // col tiles: 8 (L1) or 4 (L2)
    int wid  = threadIdx.x >> 6;
    int lane = threadIdx.x & 63;
    int row0 = gb * 64 + wid * 16;
    int lr   = lane & 15;              // M-row within tile (A) / N-col (B)
    int ks   = (lane >> 4) * 8;        // k-slice base within 32-k subtile

    int arow = row0 + lr;
    arow = arow < n_rows ? arow : n_rows - 1;   // clamp tail, stores guarded

    f16x8 a0, a1, a2, a3;
    if constexpr (XF32) {
        const float* ap = (const float*)Ain + (long)arow * K + ks;
        a0 = load_cvt8(ap);
        a1 = load_cvt8(ap + 32);
        a2 = load_cvt8(ap + 64);
        a3 = load_cvt8(ap + 96);
    } else {
        const __half* ap = (const __half*)Ain + (long)arow * K + ks;
        a0 = *(const f16x8*)(ap);
        a1 = *(const f16x8*)(ap + 32);
        a2 = *(const f16x8*)(ap + 64);
        a3 = *(const f16x8*)(ap + 96);
    }

    f32x4 acc[NT];
#pragma unroll
    for (int j = 0; j < NT; ++j) acc[j] = (f32x4)(0.f);

#pragma unroll
    for (int j = 0; j < NT; ++j) {
        const __half* bp = Bt + (long)(j * 16 + lr) * K + ks;
        f16x8 b0 = *(const f16x8*)(bp);
        f16x8 b1 = *(const f16x8*)(bp + 32);
        f16x8 b2 = *(const f16x8*)(bp + 64);
        f16x8 b3 = *(const f16x8*)(bp + 96);
        acc[j] = __builtin_amdgcn_mfma_f32_16x16x32_f16(a0, b0, acc[j], 0, 0, 0);
        acc[j] = __builtin_amdgcn_mfma_f32_16x16x32_f16(a1, b1, acc[j], 0, 0, 0);
        acc[j] = __builtin_amdgcn_mfma_f32_16x16x32_f16(a2, b2, acc[j], 0, 0, 0);
        acc[j] = __builtin_amdgcn_mfma_f32_16x16x32_f16(a3, b3, acc[j], 0, 0, 0);
    }

    // per-lane attention-vector slice (flat index j*16+lr works for both D)
    float asv[NT], adv[NT];
#pragma unroll
    for (int j = 0; j < NT; ++j) {
        asv[j] = a_s[j * 16 + lr];
        adv[j] = a_d[j * 16 + lr];
    }

    // per-wave LDS staging tile (16 rows x OUTC halves; 4 waves/block)
    __shared__ __half stg[4][16 * OUTC];
    __half* sp_ = stg[wid];

    int rbase4 = (lane >> 4) * 4;      // local row base within the wave tile
#pragma unroll
    for (int r = 0; r < 4; ++r) {
        int lrow = rbase4 + r;

        // ---- h staged to LDS (replaces scattered 2B global stores) ----
#pragma unroll
        for (int j = 0; j < NT; ++j)
            sp_[lrow * OUTC + j * 16 + lr] = __float2half(acc[j][r]);

        int rr = row0 + lrow;
        bool valid = rr < n_rows;

        // ---- fused scores: DPP row reduction (sums -> high lanes) ----
        float ps[NT], pd[NT];
#pragma unroll
        for (int j = 0; j < NT; ++j) {
            ps[j] = acc[j][r] * asv[j];
            pd[j] = acc[j][r] * adv[j];
        }
        if constexpr (D == 16) {
#pragma unroll
            for (int j = 0; j < NT; ++j) {
                ps[j] = dpp_add<0x118>(ps[j]); ps[j] = dpp_add<0x114>(ps[j]);
                ps[j] = dpp_add<0x112>(ps[j]); ps[j] = dpp_add<0x111>(ps[j]);
                pd[j] = dpp_add<0x118>(pd[j]); pd[j] = dpp_add<0x114>(pd[j]);
                pd[j] = dpp_add<0x112>(pd[j]); pd[j] = dpp_add<0x111>(pd[j]);
            }
            // lane 15 of each 16-row holds the row sum -> 2x 32B stores
            if (valid && lr == 15) {
                float* sp = s_src + rr * 8;
                float* dp = s_dst + rr * 8;
                *(float4*)(sp)     = make_float4(ps[0], ps[1], ps[2], ps[3]);
                *(float4*)(sp + 4) = make_float4(ps[4], ps[5], ps[6], ps[7]);
                *(float4*)(dp)     = make_float4(pd[0], pd[1], pd[2], pd[3]);
                *(float4*)(dp + 4) = make_float4(pd[4], pd[5], pd[6], pd[7]);
            }
        } else {
#pragma unroll
            for (int j = 0; j < NT; ++j) {
                ps[j] = dpp_add<0x114>(ps[j]); ps[j] = dpp_add<0x112>(ps[j]);
                ps[j] = dpp_add<0x111>(ps[j]);
                pd[j] = dpp_add<0x114>(pd[j]); pd[j] = dpp_add<0x112>(pd[j]);
                pd[j] = dpp_add<0x111>(pd[j]);
            }
            // lane 7: sum of lanes 0-7 (head 2j); lane 15: lanes 8-15 (head 2j+1)
            if (valid && lr == 7) {
#pragma unroll
                for (int j = 0; j < NT; ++j) {
                    s_src[rr * 8 + 2 * j] = ps[j];
                    s_dst[rr * 8 + 2 * j] = pd[j];
                }
            }
            if (valid && lr == 15) {
#pragma unroll
                for (int j = 0; j < NT; ++j) {
                    s_src[rr * 8 + 2 * j + 1] = ps[j];
                    s_dst[rr * 8 + 2 * j + 1] = pd[j];
                }
            }
        }
    }

    // ---- wide h store: the wave's 16xOUTC tile is contiguous in C ----
    constexpr int CPR = OUTC / 8;      // 16B chunks per row
    constexpr int CPL = 2 * OUTC / 64; // chunks per lane: 4 (L1) / 2 (L2)
#pragma unroll
    for (int t = 0; t < CPL; ++t) {
        int c = t * 64 + lane;         // consecutive lanes -> consecutive chunks
        int row = c / CPR;
        if (row0 + row < n_rows) {
            half8 v = *(half8*)(sp_ + c * 8);
            *(half8*)(C + (long)row0 * OUTC + c * 8) = v;
        }
    }
}

// ---------------------------------------------------------------------------
// Weight transpose/cast + bcursor zeroing (first dispatch).
// ---------------------------------------------------------------------------
__global__ __launch_bounds__(256)
void convert_w_kernel(const float* __restrict__ W1, const float* __restrict__ W2,
                      __half* __restrict__ Wt1, __half* __restrict__ Wt2,
                      int* __restrict__ bcursor) {
    int idx = blockIdx.x * 256 + threadIdx.x;
    if (idx < NBKT * BCSTRIDE) bcursor[idx] = 0;
    if (idx < 128 * 128) {
        int k = idx / 128, j = idx % 128;
        Wt1[(long)j * 128 + k] = __float2half(W1[idx]);
    } else {
        int i = idx - 128 * 128;
        if (i < 128 * 64) {
            int k = i / 64, j = i % 64;
            Wt2[(long)j * 128 + k] = __float2half(W2[i]);
        }
    }
}

// ---------------------------------------------------------------------------
// CSR phase 1: fixed-capacity bucket partition (R19/R20/R21).
// ---------------------------------------------------------------------------
__global__ __launch_bounds__(256)
void partition_kernel(const int* __restrict__ src, const int* __restrict__ dst,
                      int* __restrict__ bcursor, int2* __restrict__ bpairs) {
    constexpr int EPT = PART_CHUNK / 256;   // 16 edges per thread
    __shared__ int hist[NBKT];
    for (int i = threadIdx.x; i < NBKT; i += 256) hist[i] = 0;
    __syncthreads();
    int e0 = blockIdx.x * PART_CHUNK;
    int sv[EPT], dv[EPT];
#pragma unroll
    for (int j = 0; j < EPT; ++j) {
        int e = e0 + j * 256 + threadIdx.x;
        bool ok = e < N_EDGES;
        dv[j] = ok ? dst[e] : -1;
        sv[j] = ok ? src[e] : 0;
    }
#pragma unroll
    for (int j = 0; j < EPT; ++j)
        if (dv[j] >= 0) atomicAdd(&hist[dv[j] >> 8], 1);
    __syncthreads();
    // reserve a contiguous range per (block, bucket): one global atomic each
    for (int i = threadIdx.x; i < NBKT; i += 256) {
        int c = hist[i];
        if (c) {
            int r = atomicAdd(&bcursor[i * BCSTRIDE], c);
            hist[i] = i * BCAP + (r < BCAP ? r : BCAP);
        }
    }
    __syncthreads();
#pragma unroll
    for (int j = 0; j < EPT; ++j) {
        if (dv[j] >= 0) {
            int bkt = dv[j] >> 8;
            int pos = atomicAdd(&hist[bkt], 1);
            if (pos < (bkt + 1) * BCAP)       // overflow guard (never fires)
                bpairs[pos] = make_int2(sv[j], dv[j]);
        }
    }
}

// ---------------------------------------------------------------------------
// R20 merged dispatch: blocks [0, NBKT) run CSR phase 2 (localcsr); blocks
// [NBKT, NBKT+GEMM1_BLOCKS) run the layer-1 GEMM (independent work streams).
// ---------------------------------------------------------------------------
__global__ __launch_bounds__(256)
void localcsr_gemm1_kernel(const int* __restrict__ bcursor,
                           const int2* __restrict__ bpairs,
                           int* __restrict__ row_start, int* __restrict__ row_end,
                           int* __restrict__ eidx,
                           const float* __restrict__ x, const __half* __restrict__ Wt1,
                           __half* __restrict__ C,
                           const float* __restrict__ a_s, const float* __restrict__ a_d,
                           float* __restrict__ s_src, float* __restrict__ s_dst) {
    if (blockIdx.x >= NBKT) {
        gemm_body<128, D1, true>(blockIdx.x - NBKT, x, Wt1, C,
                                 a_s, a_d, s_src, s_dst, N_NODES);
        return;
    }
    // ---- localcsr body (R19-verified) ----
    __shared__ int cnt[256];
    __shared__ int sh[256];
    __shared__ int cur[256];
    int b = blockIdx.x;
    int tid = threadIdx.x;
    int n0 = b << 8;
    int m0 = b * BCAP;
    int count = bcursor[b * BCSTRIDE];
    int m1 = m0 + (count < BCAP ? count : BCAP);
    cnt[tid] = 0;
    __syncthreads();
    for (int k = m0 + tid; k < m1; k += 256)
        atomicAdd(&cnt[bpairs[k].y & 255], 1);
    __syncthreads();
    int c = cnt[tid];
    sh[tid] = c;
    __syncthreads();
    int run = c;
    for (int off = 1; off < 256; off <<= 1) {
        int add = (tid >= off) ? sh[tid - off] : 0;
        __syncthreads();
        run += add;
        sh[tid] = run;
        __syncthreads();
    }
    int excl = run - c;
    cur[tid] = m0 + excl;
    if (n0 + tid < N_NODES) {
        row_start[n0 + tid] = m0 + excl;
        row_end[n0 + tid]   = m0 + excl + c;
    }
    __syncthreads();
    for (int k = m0 + tid; k < m1; k += 256) {
        int2 p = bpairs[k];
        int pos = atomicAdd(&cur[p.y & 255], 1);
        eidx[pos] = p.x;
    }
}

// ---------------------------------------------------------------------------
// Standalone layer-2 GEMM (reads fp16 h1out; scores fused via DPP).
// ---------------------------------------------------------------------------
__global__ __launch_bounds__(256)
void gemm2_kernel(const __half* __restrict__ A, const __half* __restrict__ Bt,
                  __half* __restrict__ C,
                  const float* __restrict__ a_s, const float* __restrict__ a_d,
                  float* __restrict__ s_src, float* __restrict__ s_dst) {
    gemm_body<64, D2, false>(blockIdx.x, A, Bt, C, a_s, a_d, s_src, s_dst, N_NODES);
}

// ---------------------------------------------------------------------------
// Wave-per-node aggregation (R23 form: readlane for wave-uniform si, scalar
// gather base; R24's wide-gather restructure REVERTED — it was -6.6us).
// The aggregate is at its wall: 6 independent levers (bytes/MLP/VALU/SALU/
// VMEM-count/layout) leave it pinned at ~80us.
// R25: node-range split (node0..node_end) — pure diagnostic partitioning so
// ~27us pieces stop monopolizing the top-5 table and the middle kernels
// become visible. Identical per-node math.
// ---------------------------------------------------------------------------
template<int D, bool RELU, typename OT>
__global__ __launch_bounds__(256)
void aggregate_wave_kernel(const int* __restrict__ rs, const int* __restrict__ re,
                           const int* __restrict__ eidx,
                           const __half* __restrict__ h,
                           const float* __restrict__ ssrc, const float* __restrict__ sdst,
                           const float* __restrict__ bias, OT* __restrict__ out,
                           int node0, int node_end) {
    constexpr int F = HEADS * D;       // 128 or 64
    constexpr int EPL = F / 64;        // elements per lane: 2 or 1
    int lane = threadIdx.x & 63;
    int node = node0 + blockIdx.x * 4 + (threadIdx.x >> 6);
    node = __builtin_amdgcn_readfirstlane(node);
    if (node >= node_end) return;
    int hd = lane >> 3;                // head owning this lane's slice
    int esl = lane & 7;                // edge slot this lane scores

    float sdv = sdst[node * HEADS + hd];
    float sc0 = ssrc[node * HEADS + hd] + sdv;
    float w0 = __expf(sc0 > 0.f ? sc0 : NEG_SLOPE * sc0);
    float wsum = w0;

    float accx, accy = 0.f;
    if constexpr (EPL == 2) {
        float2 v = __half22float2(*(const __half2*)(h + (long)node * F + lane * 2));
        accx = w0 * v.x; accy = w0 * v.y;
    } else {
        accx = w0 * __half2float(h[(long)node * F + lane]);
    }

    int e0 = rs[node], e1 = re[node];
    int e1m1 = e1 - 1;

    for (int e = e0; e < e1; e += 8) {
        int idx = e + esl;
        int ci = idx < e1m1 ? idx : e1m1;          // clamp: address stays valid
        int s_mine = eidx[ci];                     // same 8 values in every group
        float sc = ssrc[s_mine * HEADS + hd] + sdv;
        float w_mine = __expf(sc > 0.f ? sc : NEG_SLOPE * sc);
        w_mine = (idx < e1) ? w_mine : 0.f;        // kill tail slots

        int grp = lane & 56;                       // base lane of my head row
#pragma unroll
        for (int i = 0; i < 8; ++i) {
            // si is wave-uniform (slot i identical across groups): SGPR via
            // readlane; gather becomes scalar-base + lane-offset.
            int si = (int)__builtin_amdgcn_readlane((unsigned)s_mine, i);
            float wi = __shfl(w_mine, grp + i, 64);
            wsum += wi;
            if constexpr (EPL == 2) {
                const __half2* hp = (const __half2*)(h + (long)si * F) + lane;
                float2 v = __half22float2(*hp);
                accx = fmaf(wi, v.x, accx);
                accy = fmaf(wi, v.y, accy);
            } else {
                accx = fmaf(wi, __half2float(h[(long)si * F + lane]), accx);
            }
        }
    }

    float inv = 1.f / (wsum + 1e-16f);
    if constexpr (EPL == 2) {
        float2 b = *(const float2*)(bias + lane * 2);
        float ox = accx * inv + b.x;
        float oy = accy * inv + b.y;
        if (RELU) { ox = fmaxf(ox, 0.f); oy = fmaxf(oy, 0.f); }
        if constexpr (sizeof(OT) == 2) {
            *(__half2*)((__half*)out + (long)node * F + lane * 2) = __floats2half2_rn(ox, oy);
        } else {
            *(float2*)((float*)out + (long)node * F + lane * 2) = make_float2(ox, oy);
        }
    } else {
        float o = accx * inv + bias[lane];
        if (RELU) o = fmaxf(o, 0.f);
        if constexpr (sizeof(OT) == 2) {
            ((__half*)out)[(long)node * F + lane] = __float2half(o);
        } else {
            ((float*)out)[(long)node * F + lane] = o;
        }
    }
}

extern "C" void kernel_launch(void* const* d_in, const int* in_sizes, int n_in,
                              void* d_out, int out_size, void* d_ws, size_t ws_size,
                              hipStream_t stream) {
    const float* x   = (const float*)d_in[0];
    const int*   ei  = (const int*)d_in[1];      // [2, N_EDGES] row-major
    const float* W1  = (const float*)d_in[2];
    const float* a1s = (const float*)d_in[3];
    const float* a1d = (const float*)d_in[4];
    const float* b1  = (const float*)d_in[5];
    const float* W2  = (const float*)d_in[6];
    const float* a2s = (const float*)d_in[7];
    const float* a2d = (const float*)d_in[8];
    const float* b2  = (const float*)d_in[9];
    float* out = (float*)d_out;

    const int* src = ei;
    const int* dst = ei + N_EDGES;

    // ---- workspace layout (R19) ----
    float* ws = (float*)d_ws;
    float* bufA = ws;                                  // 51.2MB slot:
                                                       //   [0..25.6MB) h1/h2 fp16
                                                       //   [32MB..41.6MB) padded eidx
    float* bufB = bufA + (size_t)N_NODES * 128;        // 51.2MB slot, time-shared:
                                                       //   padded bpairs (19.2MB) -> h1out
    float* ssrc = bufB + (size_t)N_NODES * 128;        // N*8
    float* sdst = ssrc + (size_t)N_NODES * HEADS;      // N*8
    int* counts    = (int*)(sdst + (size_t)N_NODES * HEADS);  // N ints (carved below)
    int* row_start = counts + N_NODES;                 // N+1
    int* row_end   = row_start + N_NODES + 1;          // N

    int* bcursor = counts + 1024;            // NBKT*BCSTRIDE ints (line-padded)
    __half* Wt1  = (__half*)(counts + 1024 + NBKT * BCSTRIDE);          // 8192 ints
    __half* Wt2  = (__half*)(counts + 1024 + NBKT * BCSTRIDE + 8192);   // 4096 ints
    int2* bpairs  = (int2*)bufB;             // NBKT*BCAP*8B = 19.2MB; dead before h1out
    __half* h1out = (__half*)bufB;           // N*128 fp16; written by agg L1
    int* eidx = (int*)((char*)bufA + (size_t)32 * 1024 * 1024);  // NBKT*BCAP ints = 9.6MB

    __half* hbuf = (__half*)bufA;

    // ---- dispatches (aggregates 3-way split for top-5 visibility) ----
    convert_w_kernel<<<(128 * 128 + 128 * 64 + 255) / 256, 256, 0, stream>>>(
        W1, W2, Wt1, Wt2, bcursor);
    partition_kernel<<<(N_EDGES + PART_CHUNK - 1) / PART_CHUNK, 256, 0, stream>>>(
        src, dst, bcursor, bpairs);
    // merged: CSR phase 2 (391 blocks) || layer-1 GEMM (1563 blocks)
    localcsr_gemm1_kernel<<<NBKT + GEMM1_BLOCKS, 256, 0, stream>>>(
        bcursor, bpairs, row_start, row_end, eidx,
        x, Wt1, hbuf, a1s, a1d, ssrc, sdst);
    for (int c = 0; c < 3; ++c) {
        int n0 = c * AGG_CHUNK;
        int n1 = (n0 + AGG_CHUNK < N_NODES) ? n0 + AGG_CHUNK : N_NODES;
        aggregate_wave_kernel<D1, true, __half><<<(n1 - n0 + 3) / 4, 256, 0, stream>>>(
            row_start, row_end, eidx, hbuf, ssrc, sdst, b1, h1out, n0, n1);
    }
    gemm2_kernel<<<GEMM1_BLOCKS, 256, 0, stream>>>(
        h1out, Wt2, hbuf, a2s, a2d, ssrc, sdst);
    for (int c = 0; c < 3; ++c) {
        int n0 = c * AGG_CHUNK;
        int n1 = (n0 + AGG_CHUNK < N_NODES) ? n0 + AGG_CHUNK : N_NODES;
        aggregate_wave_kernel<D2, false, float><<<(n1 - n0 + 3) / 4, 256, 0, stream>>>(
            row_start, row_end, eidx, hbuf, ssrc, sdst, b2, out, n0, n1);
    }
}

// Round 16
// 321.699 us; speedup vs baseline: 1.0819x; 1.0819x over previous
//
#include <hip/hip_runtime.h>
#include <hip/hip_fp16.h>
#include <math.h>

#define N_NODES 100000
#define N_EDGES 1600000
#define IN_DIM 128
#define HEADS 8
#define D1 16
#define D2 8
#define NEG_SLOPE 0.2f

#define NBKT ((N_NODES + 255) / 256)      // 391 buckets of 256 dst nodes
#define PART_CHUNK 4096                   // R16 lesson: bigger chunks -> occupancy collapse
#define NPART ((N_EDGES + PART_CHUNK - 1) / PART_CHUNK)   // 391 partition blocks
#define NCONV ((128 * 128 + 128 * 64 + 255) / 256)        // 96 convert blocks
#define BCAP 6144                         // R19: fixed bucket capacity = mean 4096 + 32 sigma
#define BCSTRIDE 32                       // R21: one 128B line per bucket cursor (kept; free)
#define GEMM1_BLOCKS ((N_NODES + 63) / 64)

typedef _Float16 f16x8 __attribute__((ext_vector_type(8)));
typedef float    f32x4 __attribute__((ext_vector_type(4)));

// 16-byte pack of 8 halves.
struct __align__(16) half8 { __half2 a, b, c, d; };

__device__ __forceinline__ f16x8 load_cvt8(const float* p) {
    float4 v0 = *(const float4*)p, v1 = *(const float4*)(p + 4);
    f16x8 r;
    r[0] = (_Float16)v0.x; r[1] = (_Float16)v0.y;
    r[2] = (_Float16)v0.z; r[3] = (_Float16)v0.w;
    r[4] = (_Float16)v1.x; r[5] = (_Float16)v1.y;
    r[6] = (_Float16)v1.z; r[7] = (_Float16)v1.w;
    return r;
}

// DPP row_shr:N add (VALU only). bound_ctrl=true: OOB reads 0.
// row_shr:N: lane i reads lane i-N — accumulation flows toward HIGHER lanes;
// after shr 8,4,2,1 the 16-lane row sum is in lane 15 (R17 bug: stored from
// lane 0). 8-lane group sums land in lanes 7 and 15.
template<int CTRL>
__device__ __forceinline__ float dpp_add(float x) {
    int y = __builtin_amdgcn_update_dpp(0, __builtin_bit_cast(int, x),
                                        CTRL, 0xF, 0xF, true);
    return x + __builtin_bit_cast(float, y);
}

// ---------------------------------------------------------------------------
// MFMA GEMM body + fused score epilogue (DPP reduce, R18-verified; R22 LDS
// restage for wide coalesced h-stores).
// Fragment pattern (guide m90/m92, HW-verified):
//   A-frag: lane reads A[row0+(lane&15)][ks..ks+8), ks=(lane>>4)*8 per 32-k step
//   B-frag: same from Bt rows (Bt = W^T)
//   C/D  : row=(lane>>4)*4+r, col=j*16+(lane&15)
// Score fusion: col j*16+lr == head*D+d flat for BOTH layers.
// XF32: layer-1 reads x fp32, converts in-register (RN, == old convert_x).
// ---------------------------------------------------------------------------
template<int OUTC, int D, bool XF32>
__device__ __forceinline__ void gemm_body(int gb, const void* __restrict__ Ain,
                                          const __half* __restrict__ Bt,
                                          __half* __restrict__ C,
                                          const float* __restrict__ a_s,
                                          const float* __restrict__ a_d,
                                          float* __restrict__ s_src,
                                          float* __restrict__ s_dst,
                                          int n_rows) {
    constexpr int K = 128;
    constexpr int NT = OUTC / 16;      // col tiles: 8 (L1) or 4 (L2)
    int wid  = threadIdx.x >> 6;
    int lane = threadIdx.x & 63;
    int row0 = gb * 64 + wid * 16;
    int lr   = lane & 15;              // M-row within tile (A) / N-col (B)
    int ks   = (lane >> 4) * 8;        // k-slice base within 32-k subtile

    int arow = row0 + lr;
    arow = arow < n_rows ? arow : n_rows - 1;   // clamp tail, stores guarded

    f16x8 a0, a1, a2, a3;
    if constexpr (XF32) {
        const float* ap = (const float*)Ain + (long)arow * K + ks;
        a0 = load_cvt8(ap);
        a1 = load_cvt8(ap + 32);
        a2 = load_cvt8(ap + 64);
        a3 = load_cvt8(ap + 96);
    } else {
        const __half* ap = (const __half*)Ain + (long)arow * K + ks;
        a0 = *(const f16x8*)(ap);
        a1 = *(const f16x8*)(ap + 32);
        a2 = *(const f16x8*)(ap + 64);
        a3 = *(const f16x8*)(ap + 96);
    }

    f32x4 acc[NT];
#pragma unroll
    for (int j = 0; j < NT; ++j) acc[j] = (f32x4)(0.f);

#pragma unroll
    for (int j = 0; j < NT; ++j) {
        const __half* bp = Bt + (long)(j * 16 + lr) * K + ks;
        f16x8 b0 = *(const f16x8*)(bp);
        f16x8 b1 = *(const f16x8*)(bp + 32);
        f16x8 b2 = *(const f16x8*)(bp + 64);
        f16x8 b3 = *(const f16x8*)(bp + 96);
        acc[j] = __builtin_amdgcn_mfma_f32_16x16x32_f16(a0, b0, acc[j], 0, 0, 0);
        acc[j] = __builtin_amdgcn_mfma_f32_16x16x32_f16(a1, b1, acc[j], 0, 0, 0);
        acc[j] = __builtin_amdgcn_mfma_f32_16x16x32_f16(a2, b2, acc[j], 0, 0, 0);
        acc[j] = __builtin_amdgcn_mfma_f32_16x16x32_f16(a3, b3, acc[j], 0, 0, 0);
    }

    // per-lane attention-vector slice (flat index j*16+lr works for both D)
    float asv[NT], adv[NT];
#pragma unroll
    for (int j = 0; j < NT; ++j) {
        asv[j] = a_s[j * 16 + lr];
        adv[j] = a_d[j * 16 + lr];
    }

    // per-wave LDS staging tile (16 rows x OUTC halves; 4 waves/block)
    __shared__ __half stg[4][16 * OUTC];
    __half* sp_ = stg[wid];

    int rbase4 = (lane >> 4) * 4;      // local row base within the wave tile
#pragma unroll
    for (int r = 0; r < 4; ++r) {
        int lrow = rbase4 + r;

        // ---- h staged to LDS (replaces scattered 2B global stores) ----
#pragma unroll
        for (int j = 0; j < NT; ++j)
            sp_[lrow * OUTC + j * 16 + lr] = __float2half(acc[j][r]);

        int rr = row0 + lrow;
        bool valid = rr < n_rows;

        // ---- fused scores: DPP row reduction (sums -> high lanes) ----
        float ps[NT], pd[NT];
#pragma unroll
        for (int j = 0; j < NT; ++j) {
            ps[j] = acc[j][r] * asv[j];
            pd[j] = acc[j][r] * adv[j];
        }
        if constexpr (D == 16) {
#pragma unroll
            for (int j = 0; j < NT; ++j) {
                ps[j] = dpp_add<0x118>(ps[j]); ps[j] = dpp_add<0x114>(ps[j]);
                ps[j] = dpp_add<0x112>(ps[j]); ps[j] = dpp_add<0x111>(ps[j]);
                pd[j] = dpp_add<0x118>(pd[j]); pd[j] = dpp_add<0x114>(pd[j]);
                pd[j] = dpp_add<0x112>(pd[j]); pd[j] = dpp_add<0x111>(pd[j]);
            }
            // lane 15 of each 16-row holds the row sum -> 2x 32B stores
            if (valid && lr == 15) {
                float* sp = s_src + rr * 8;
                float* dp = s_dst + rr * 8;
                *(float4*)(sp)     = make_float4(ps[0], ps[1], ps[2], ps[3]);
                *(float4*)(sp + 4) = make_float4(ps[4], ps[5], ps[6], ps[7]);
                *(float4*)(dp)     = make_float4(pd[0], pd[1], pd[2], pd[3]);
                *(float4*)(dp + 4) = make_float4(pd[4], pd[5], pd[6], pd[7]);
            }
        } else {
#pragma unroll
            for (int j = 0; j < NT; ++j) {
                ps[j] = dpp_add<0x114>(ps[j]); ps[j] = dpp_add<0x112>(ps[j]);
                ps[j] = dpp_add<0x111>(ps[j]);
                pd[j] = dpp_add<0x114>(pd[j]); pd[j] = dpp_add<0x112>(pd[j]);
                pd[j] = dpp_add<0x111>(pd[j]);
            }
            // lane 7: sum of lanes 0-7 (head 2j); lane 15: lanes 8-15 (head 2j+1)
            if (valid && lr == 7) {
#pragma unroll
                for (int j = 0; j < NT; ++j) {
                    s_src[rr * 8 + 2 * j] = ps[j];
                    s_dst[rr * 8 + 2 * j] = pd[j];
                }
            }
            if (valid && lr == 15) {
#pragma unroll
                for (int j = 0; j < NT; ++j) {
                    s_src[rr * 8 + 2 * j + 1] = ps[j];
                    s_dst[rr * 8 + 2 * j + 1] = pd[j];
                }
            }
        }
    }

    // ---- wide h store: the wave's 16xOUTC tile is contiguous in C ----
    constexpr int CPR = OUTC / 8;      // 16B chunks per row
    constexpr int CPL = 2 * OUTC / 64; // chunks per lane: 4 (L1) / 2 (L2)
#pragma unroll
    for (int t = 0; t < CPL; ++t) {
        int c = t * 64 + lane;         // consecutive lanes -> consecutive chunks
        int row = c / CPR;
        if (row0 + row < n_rows) {
            half8 v = *(half8*)(sp_ + c * 8);
            *(half8*)(C + (long)row0 * OUTC + c * 8) = v;
        }
    }
}

// ---------------------------------------------------------------------------
// R26 merged front: blocks [0, NPART) run partition; blocks [NPART,
// NPART+NCONV) run the weight transpose/cast (independent work; bcursor
// zeroing moved to hipMemsetAsync). Saves one dispatch gap (~4.3us, R25
// measurement: +4 dispatches cost +17.3us).
// ---------------------------------------------------------------------------
__global__ __launch_bounds__(256)
void partition_convw_kernel(const int* __restrict__ src, const int* __restrict__ dst,
                            int* __restrict__ bcursor, int2* __restrict__ bpairs,
                            const float* __restrict__ W1, const float* __restrict__ W2,
                            __half* __restrict__ Wt1, __half* __restrict__ Wt2) {
    if (blockIdx.x >= NPART) {
        int idx = (blockIdx.x - NPART) * 256 + threadIdx.x;
        if (idx < 128 * 128) {
            int k = idx / 128, j = idx % 128;
            Wt1[(long)j * 128 + k] = __float2half(W1[idx]);
        } else {
            int i = idx - 128 * 128;
            if (i < 128 * 64) {
                int k = i / 64, j = i % 64;
                Wt2[(long)j * 128 + k] = __float2half(W2[i]);
            }
        }
        return;
    }
    constexpr int EPT = PART_CHUNK / 256;   // 16 edges per thread
    __shared__ int hist[NBKT];
    for (int i = threadIdx.x; i < NBKT; i += 256) hist[i] = 0;
    __syncthreads();
    int e0 = blockIdx.x * PART_CHUNK;
    int sv[EPT], dv[EPT];
#pragma unroll
    for (int j = 0; j < EPT; ++j) {
        int e = e0 + j * 256 + threadIdx.x;
        bool ok = e < N_EDGES;
        dv[j] = ok ? dst[e] : -1;
        sv[j] = ok ? src[e] : 0;
    }
#pragma unroll
    for (int j = 0; j < EPT; ++j)
        if (dv[j] >= 0) atomicAdd(&hist[dv[j] >> 8], 1);
    __syncthreads();
    // reserve a contiguous range per (block, bucket): one global atomic each
    for (int i = threadIdx.x; i < NBKT; i += 256) {
        int c = hist[i];
        if (c) {
            int r = atomicAdd(&bcursor[i * BCSTRIDE], c);
            hist[i] = i * BCAP + (r < BCAP ? r : BCAP);
        }
    }
    __syncthreads();
#pragma unroll
    for (int j = 0; j < EPT; ++j) {
        if (dv[j] >= 0) {
            int bkt = dv[j] >> 8;
            int pos = atomicAdd(&hist[bkt], 1);
            if (pos < (bkt + 1) * BCAP)       // overflow guard (never fires)
                bpairs[pos] = make_int2(sv[j], dv[j]);
        }
    }
}

// ---------------------------------------------------------------------------
// R20 merged dispatch: blocks [0, NBKT) run CSR phase 2 (localcsr); blocks
// [NBKT, NBKT+GEMM1_BLOCKS) run the layer-1 GEMM.
// R25 measurement: this kernel = 53us, MfmaUtil 2%, VALUBusy 12%, occupancy
// 30% — latency-bound, suspected localcsr serial-chain tail (16 dependent
// load->LDS-atomic iterations x2 passes). R26: int4 paired loads halve the
// chain length (2 pairs per dependent load, 8 iterations/pass).
// ---------------------------------------------------------------------------
__global__ __launch_bounds__(256)
void localcsr_gemm1_kernel(const int* __restrict__ bcursor,
                           const int2* __restrict__ bpairs,
                           int* __restrict__ row_start, int* __restrict__ row_end,
                           int* __restrict__ eidx,
                           const float* __restrict__ x, const __half* __restrict__ Wt1,
                           __half* __restrict__ C,
                           const float* __restrict__ a_s, const float* __restrict__ a_d,
                           float* __restrict__ s_src, float* __restrict__ s_dst) {
    if (blockIdx.x >= NBKT) {
        gemm_body<128, D1, true>(blockIdx.x - NBKT, x, Wt1, C,
                                 a_s, a_d, s_src, s_dst, N_NODES);
        return;
    }
    // ---- localcsr body (R19-verified; R26 int4-paired) ----
    __shared__ int cnt[256];
    __shared__ int sh[256];
    __shared__ int cur[256];
    int b = blockIdx.x;
    int tid = threadIdx.x;
    int n0 = b << 8;
    int m0 = b * BCAP;                       // even -> int4-aligned
    int count = bcursor[b * BCSTRIDE];
    int m1 = m0 + (count < BCAP ? count : BCAP);
    bool odd = ((m1 - m0) & 1) != 0;
    cnt[tid] = 0;
    __syncthreads();
    for (int k = m0 + tid * 2; k + 1 < m1; k += 512) {
        int4 pp = *(const int4*)(bpairs + k);      // 2 pairs per load
        atomicAdd(&cnt[pp.y & 255], 1);
        atomicAdd(&cnt[pp.w & 255], 1);
    }
    if (tid == 0 && odd) atomicAdd(&cnt[bpairs[m1 - 1].y & 255], 1);
    __syncthreads();
    int c = cnt[tid];
    sh[tid] = c;
    __syncthreads();
    int run = c;
    for (int off = 1; off < 256; off <<= 1) {
        int add = (tid >= off) ? sh[tid - off] : 0;
        __syncthreads();
        run += add;
        sh[tid] = run;
        __syncthreads();
    }
    int excl = run - c;
    cur[tid] = m0 + excl;
    if (n0 + tid < N_NODES) {
        row_start[n0 + tid] = m0 + excl;
        row_end[n0 + tid]   = m0 + excl + c;
    }
    __syncthreads();
    for (int k = m0 + tid * 2; k + 1 < m1; k += 512) {
        int4 pp = *(const int4*)(bpairs + k);
        int pos0 = atomicAdd(&cur[pp.y & 255], 1);
        eidx[pos0] = pp.x;
        int pos1 = atomicAdd(&cur[pp.w & 255], 1);
        eidx[pos1] = pp.z;
    }
    if (tid == 0 && odd) {
        int2 p = bpairs[m1 - 1];
        int pos = atomicAdd(&cur[p.y & 255], 1);
        eidx[pos] = p.x;
    }
}

// ---------------------------------------------------------------------------
// Standalone layer-2 GEMM (reads fp16 h1out; scores fused via DPP).
// ---------------------------------------------------------------------------
__global__ __launch_bounds__(256)
void gemm2_kernel(const __half* __restrict__ A, const __half* __restrict__ Bt,
                  __half* __restrict__ C,
                  const float* __restrict__ a_s, const float* __restrict__ a_d,
                  float* __restrict__ s_src, float* __restrict__ s_dst) {
    gemm_body<64, D2, false>(blockIdx.x, A, Bt, C, a_s, a_d, s_src, s_dst, N_NODES);
}

// ---------------------------------------------------------------------------
// Wave-per-node aggregation (R23 form, best measured: readlane for
// wave-uniform si, scalar gather base). At its wall — 6 independent levers
// (bytes/MLP/VALU/SALU/VMEM-count/layout) leave it pinned at ~80us.
// R26: un-split (R25's 3-way diagnostic split cost ~17us in dispatch gaps).
// ---------------------------------------------------------------------------
template<int D, bool RELU, typename OT>
__global__ __launch_bounds__(256)
void aggregate_wave_kernel(const int* __restrict__ rs, const int* __restrict__ re,
                           const int* __restrict__ eidx,
                           const __half* __restrict__ h,
                           const float* __restrict__ ssrc, const float* __restrict__ sdst,
                           const float* __restrict__ bias, OT* __restrict__ out) {
    constexpr int F = HEADS * D;       // 128 or 64
    constexpr int EPL = F / 64;        // elements per lane: 2 or 1
    int lane = threadIdx.x & 63;
    int node = blockIdx.x * 4 + (threadIdx.x >> 6);
    node = __builtin_amdgcn_readfirstlane(node);
    if (node >= N_NODES) return;
    int hd = lane >> 3;                // head owning this lane's slice
    int esl = lane & 7;                // edge slot this lane scores

    float sdv = sdst[node * HEADS + hd];
    float sc0 = ssrc[node * HEADS + hd] + sdv;
    float w0 = __expf(sc0 > 0.f ? sc0 : NEG_SLOPE * sc0);
    float wsum = w0;

    float accx, accy = 0.f;
    if constexpr (EPL == 2) {
        float2 v = __half22float2(*(const __half2*)(h + (long)node * F + lane * 2));
        accx = w0 * v.x; accy = w0 * v.y;
    } else {
        accx = w0 * __half2float(h[(long)node * F + lane]);
    }

    int e0 = rs[node], e1 = re[node];
    int e1m1 = e1 - 1;

    for (int e = e0; e < e1; e += 8) {
        int idx = e + esl;
        int ci = idx < e1m1 ? idx : e1m1;          // clamp: address stays valid
        int s_mine = eidx[ci];                     // same 8 values in every group
        float sc = ssrc[s_mine * HEADS + hd] + sdv;
        float w_mine = __expf(sc > 0.f ? sc : NEG_SLOPE * sc);
        w_mine = (idx < e1) ? w_mine : 0.f;        // kill tail slots

        int grp = lane & 56;                       // base lane of my head row
#pragma unroll
        for (int i = 0; i < 8; ++i) {
            // si is wave-uniform (slot i identical across groups): SGPR via
            // readlane; gather becomes scalar-base + lane-offset.
            int si = (int)__builtin_amdgcn_readlane((unsigned)s_mine, i);
            float wi = __shfl(w_mine, grp + i, 64);
            wsum += wi;
            if constexpr (EPL == 2) {
                const __half2* hp = (const __half2*)(h + (long)si * F) + lane;
                float2 v = __half22float2(*hp);
                accx = fmaf(wi, v.x, accx);
                accy = fmaf(wi, v.y, accy);
            } else {
                accx = fmaf(wi, __half2float(h[(long)si * F + lane]), accx);
            }
        }
    }

    float inv = 1.f / (wsum + 1e-16f);
    if constexpr (EPL == 2) {
        float2 b = *(const float2*)(bias + lane * 2);
        float ox = accx * inv + b.x;
        float oy = accy * inv + b.y;
        if (RELU) { ox = fmaxf(ox, 0.f); oy = fmaxf(oy, 0.f); }
        if constexpr (sizeof(OT) == 2) {
            *(__half2*)((__half*)out + (long)node * F + lane * 2) = __floats2half2_rn(ox, oy);
        } else {
            *(float2*)((float*)out + (long)node * F + lane * 2) = make_float2(ox, oy);
        }
    } else {
        float o = accx * inv + bias[lane];
        if (RELU) o = fmaxf(o, 0.f);
        if constexpr (sizeof(OT) == 2) {
            ((__half*)out)[(long)node * F + lane] = __float2half(o);
        } else {
            ((float*)out)[(long)node * F + lane] = o;
        }
    }
}

extern "C" void kernel_launch(void* const* d_in, const int* in_sizes, int n_in,
                              void* d_out, int out_size, void* d_ws, size_t ws_size,
                              hipStream_t stream) {
    const float* x   = (const float*)d_in[0];
    const int*   ei  = (const int*)d_in[1];      // [2, N_EDGES] row-major
    const float* W1  = (const float*)d_in[2];
    const float* a1s = (const float*)d_in[3];
    const float* a1d = (const float*)d_in[4];
    const float* b1  = (const float*)d_in[5];
    const float* W2  = (const float*)d_in[6];
    const float* a2s = (const float*)d_in[7];
    const float* a2d = (const float*)d_in[8];
    const float* b2  = (const float*)d_in[9];
    float* out = (float*)d_out;

    const int* src = ei;
    const int* dst = ei + N_EDGES;

    // ---- workspace layout (R19) ----
    float* ws = (float*)d_ws;
    float* bufA = ws;                                  // 51.2MB slot:
                                                       //   [0..25.6MB) h1/h2 fp16
                                                       //   [32MB..41.6MB) padded eidx
    float* bufB = bufA + (size_t)N_NODES * 128;        // 51.2MB slot, time-shared:
                                                       //   padded bpairs (19.2MB) -> h1out
    float* ssrc = bufB + (size_t)N_NODES * 128;        // N*8
    float* sdst = ssrc + (size_t)N_NODES * HEADS;      // N*8
    int* counts    = (int*)(sdst + (size_t)N_NODES * HEADS);  // N ints (carved below)
    int* row_start = counts + N_NODES;                 // N+1
    int* row_end   = row_start + N_NODES + 1;          // N

    int* bcursor = counts + 1024;            // NBKT*BCSTRIDE ints (line-padded)
    __half* Wt1  = (__half*)(counts + 1024 + NBKT * BCSTRIDE);          // 8192 ints
    __half* Wt2  = (__half*)(counts + 1024 + NBKT * BCSTRIDE + 8192);   // 4096 ints
    int2* bpairs  = (int2*)bufB;             // NBKT*BCAP*8B = 19.2MB; dead before h1out
    __half* h1out = (__half*)bufB;           // N*128 fp16; written by agg L1
    int* eidx = (int*)((char*)bufA + (size_t)32 * 1024 * 1024);  // NBKT*BCAP ints = 9.6MB

    __half* hbuf = (__half*)bufA;

    // ---- 5 dispatches + 1 memset ----
    hipMemsetAsync(bcursor, 0, (size_t)NBKT * BCSTRIDE * sizeof(int), stream);
    // merged: partition (391 blocks) || weight convert (96 blocks)
    partition_convw_kernel<<<NPART + NCONV, 256, 0, stream>>>(
        src, dst, bcursor, bpairs, W1, W2, Wt1, Wt2);
    // merged: CSR phase 2 (391 blocks) || layer-1 GEMM (1563 blocks)
    localcsr_gemm1_kernel<<<NBKT + GEMM1_BLOCKS, 256, 0, stream>>>(
        bcursor, bpairs, row_start, row_end, eidx,
        x, Wt1, hbuf, a1s, a1d, ssrc, sdst);
    aggregate_wave_kernel<D1, true, __half><<<(N_NODES + 3) / 4, 256, 0, stream>>>(
        row_start, row_end, eidx, hbuf, ssrc, sdst, b1, h1out);
    gemm2_kernel<<<GEMM1_BLOCKS, 256, 0, stream>>>(
        h1out, Wt2, hbuf, a2s, a2d, ssrc, sdst);
    aggregate_wave_kernel<D2, false, float><<<(N_NODES + 3) / 4, 256, 0, stream>>>(
        row_start, row_end, eidx, hbuf, ssrc, sdst, b2, out);
}

// Round 17
// 320.790 us; speedup vs baseline: 1.0850x; 1.0028x over previous
//
#include <hip/hip_runtime.h>
#include <hip/hip_fp16.h>
#include <math.h>

#define N_NODES 100000
#define N_EDGES 1600000
#define IN_DIM 128
#define HEADS 8
#define D1 16
#define D2 8
#define NEG_SLOPE 0.2f

#define NBKT ((N_NODES + 255) / 256)      // 391 buckets of 256 dst nodes
#define PART_CHUNK 4096                   // R16 lesson: bigger chunks -> occupancy collapse
#define NPART ((N_EDGES + PART_CHUNK - 1) / PART_CHUNK)   // 391 partition blocks
#define NCONV ((128 * 128 + 128 * 64 + 255) / 256)        // 96 convert blocks
#define BCAP 6144                         // R19: fixed bucket capacity = mean 4096 + 32 sigma
#define BCSTRIDE 32                       // R21: one 128B line per bucket cursor (kept; free)
#define GEMM1_BLOCKS ((N_NODES + 63) / 64)

typedef _Float16 f16x8 __attribute__((ext_vector_type(8)));
typedef float    f32x4 __attribute__((ext_vector_type(4)));

// 16-byte pack of 8 halves.
struct __align__(16) half8 { __half2 a, b, c, d; };

__device__ __forceinline__ f16x8 load_cvt8(const float* p) {
    float4 v0 = *(const float4*)p, v1 = *(const float4*)(p + 4);
    f16x8 r;
    r[0] = (_Float16)v0.x; r[1] = (_Float16)v0.y;
    r[2] = (_Float16)v0.z; r[3] = (_Float16)v0.w;
    r[4] = (_Float16)v1.x; r[5] = (_Float16)v1.y;
    r[6] = (_Float16)v1.z; r[7] = (_Float16)v1.w;
    return r;
}

// DPP row_shr:N add (VALU only). bound_ctrl=true: OOB reads 0.
// row_shr:N: lane i reads lane i-N — accumulation flows toward HIGHER lanes;
// after shr 8,4,2,1 the 16-lane row sum is in lane 15 (R17 bug: stored from
// lane 0). 8-lane group sums land in lanes 7 and 15.
template<int CTRL>
__device__ __forceinline__ float dpp_add(float x) {
    int y = __builtin_amdgcn_update_dpp(0, __builtin_bit_cast(int, x),
                                        CTRL, 0xF, 0xF, true);
    return x + __builtin_bit_cast(float, y);
}

// ---------------------------------------------------------------------------
// MFMA GEMM body + fused score epilogue (DPP reduce, R18-verified; R22 LDS
// restage for wide coalesced h-stores). R27: the staging tile is passed in
// (hoisted __shared__) so the merged kernel can UNION it with localcsr's
// scratch — both statics summed before (19456B -> 8 blocks/CU; now 16384B).
// Fragment pattern (guide m90/m92, HW-verified):
//   A-frag: lane reads A[row0+(lane&15)][ks..ks+8), ks=(lane>>4)*8 per 32-k step
//   B-frag: same from Bt rows (Bt = W^T)
//   C/D  : row=(lane>>4)*4+r, col=j*16+(lane&15)
// Score fusion: col j*16+lr == head*D+d flat for BOTH layers.
// XF32: layer-1 reads x fp32, converts in-register (RN, == old convert_x).
// ---------------------------------------------------------------------------
template<int OUTC, int D, bool XF32>
__device__ __forceinline__ void gemm_body(int gb, const void* __restrict__ Ain,
                                          const __half* __restrict__ Bt,
                                          __half* __restrict__ C,
                                          const float* __restrict__ a_s,
                                          const float* __restrict__ a_d,
                                          float* __restrict__ s_src,
                                          float* __restrict__ s_dst,
                                          int n_rows, __half* stg) {
    constexpr int K = 128;
    constexpr int NT = OUTC / 16;      // col tiles: 8 (L1) or 4 (L2)
    int wid  = threadIdx.x >> 6;
    int lane = threadIdx.x & 63;
    int row0 = gb * 64 + wid * 16;
    int lr   = lane & 15;              // M-row within tile (A) / N-col (B)
    int ks   = (lane >> 4) * 8;        // k-slice base within 32-k subtile

    int arow = row0 + lr;
    arow = arow < n_rows ? arow : n_rows - 1;   // clamp tail, stores guarded

    f16x8 a0, a1, a2, a3;
    if constexpr (XF32) {
        const float* ap = (const float*)Ain + (long)arow * K + ks;
        a0 = load_cvt8(ap);
        a1 = load_cvt8(ap + 32);
        a2 = load_cvt8(ap + 64);
        a3 = load_cvt8(ap + 96);
    } else {
        const __half* ap = (const __half*)Ain + (long)arow * K + ks;
        a0 = *(const f16x8*)(ap);
        a1 = *(const f16x8*)(ap + 32);
        a2 = *(const f16x8*)(ap + 64);
        a3 = *(const f16x8*)(ap + 96);
    }

    f32x4 acc[NT];
#pragma unroll
    for (int j = 0; j < NT; ++j) acc[j] = (f32x4)(0.f);

#pragma unroll
    for (int j = 0; j < NT; ++j) {
        const __half* bp = Bt + (long)(j * 16 + lr) * K + ks;
        f16x8 b0 = *(const f16x8*)(bp);
        f16x8 b1 = *(const f16x8*)(bp + 32);
        f16x8 b2 = *(const f16x8*)(bp + 64);
        f16x8 b3 = *(const f16x8*)(bp + 96);
        acc[j] = __builtin_amdgcn_mfma_f32_16x16x32_f16(a0, b0, acc[j], 0, 0, 0);
        acc[j] = __builtin_amdgcn_mfma_f32_16x16x32_f16(a1, b1, acc[j], 0, 0, 0);
        acc[j] = __builtin_amdgcn_mfma_f32_16x16x32_f16(a2, b2, acc[j], 0, 0, 0);
        acc[j] = __builtin_amdgcn_mfma_f32_16x16x32_f16(a3, b3, acc[j], 0, 0, 0);
    }

    // per-lane attention-vector slice (flat index j*16+lr works for both D)
    float asv[NT], adv[NT];
#pragma unroll
    for (int j = 0; j < NT; ++j) {
        asv[j] = a_s[j * 16 + lr];
        adv[j] = a_d[j * 16 + lr];
    }

    __half* sp_ = stg + wid * 16 * OUTC;   // per-wave staging region

    int rbase4 = (lane >> 4) * 4;      // local row base within the wave tile
#pragma unroll
    for (int r = 0; r < 4; ++r) {
        int lrow = rbase4 + r;

        // ---- h staged to LDS (replaces scattered 2B global stores) ----
#pragma unroll
        for (int j = 0; j < NT; ++j)
            sp_[lrow * OUTC + j * 16 + lr] = __float2half(acc[j][r]);

        int rr = row0 + lrow;
        bool valid = rr < n_rows;

        // ---- fused scores: DPP row reduction (sums -> high lanes) ----
        float ps[NT], pd[NT];
#pragma unroll
        for (int j = 0; j < NT; ++j) {
            ps[j] = acc[j][r] * asv[j];
            pd[j] = acc[j][r] * adv[j];
        }
        if constexpr (D == 16) {
#pragma unroll
            for (int j = 0; j < NT; ++j) {
                ps[j] = dpp_add<0x118>(ps[j]); ps[j] = dpp_add<0x114>(ps[j]);
                ps[j] = dpp_add<0x112>(ps[j]); ps[j] = dpp_add<0x111>(ps[j]);
                pd[j] = dpp_add<0x118>(pd[j]); pd[j] = dpp_add<0x114>(pd[j]);
                pd[j] = dpp_add<0x112>(pd[j]); pd[j] = dpp_add<0x111>(pd[j]);
            }
            // lane 15 of each 16-row holds the row sum -> 2x 32B stores
            if (valid && lr == 15) {
                float* sp = s_src + rr * 8;
                float* dp = s_dst + rr * 8;
                *(float4*)(sp)     = make_float4(ps[0], ps[1], ps[2], ps[3]);
                *(float4*)(sp + 4) = make_float4(ps[4], ps[5], ps[6], ps[7]);
                *(float4*)(dp)     = make_float4(pd[0], pd[1], pd[2], pd[3]);
                *(float4*)(dp + 4) = make_float4(pd[4], pd[5], pd[6], pd[7]);
            }
        } else {
#pragma unroll
            for (int j = 0; j < NT; ++j) {
                ps[j] = dpp_add<0x114>(ps[j]); ps[j] = dpp_add<0x112>(ps[j]);
                ps[j] = dpp_add<0x111>(ps[j]);
                pd[j] = dpp_add<0x114>(pd[j]); pd[j] = dpp_add<0x112>(pd[j]);
                pd[j] = dpp_add<0x111>(pd[j]);
            }
            // lane 7: sum of lanes 0-7 (head 2j); lane 15: lanes 8-15 (head 2j+1)
            if (valid && lr == 7) {
#pragma unroll
                for (int j = 0; j < NT; ++j) {
                    s_src[rr * 8 + 2 * j] = ps[j];
                    s_dst[rr * 8 + 2 * j] = pd[j];
                }
            }
            if (valid && lr == 15) {
#pragma unroll
                for (int j = 0; j < NT; ++j) {
                    s_src[rr * 8 + 2 * j + 1] = ps[j];
                    s_dst[rr * 8 + 2 * j + 1] = pd[j];
                }
            }
        }
    }

    // ---- wide h store: the wave's 16xOUTC tile is contiguous in C ----
    constexpr int CPR = OUTC / 8;      // 16B chunks per row
    constexpr int CPL = 2 * OUTC / 64; // chunks per lane: 4 (L1) / 2 (L2)
#pragma unroll
    for (int t = 0; t < CPL; ++t) {
        int c = t * 64 + lane;         // consecutive lanes -> consecutive chunks
        int row = c / CPR;
        if (row0 + row < n_rows) {
            half8 v = *(half8*)(sp_ + c * 8);
            *(half8*)(C + (long)row0 * OUTC + c * 8) = v;
        }
    }
}

// ---------------------------------------------------------------------------
// R26 merged front: partition (NPART blocks) || weight convert (NCONV).
// R27: bpairs packed to ONE int: (local_dst<<24)|src — src<2^17 fits 24b,
// within-bucket dst is 8b. Halves partition scatter traffic and lets
// localcsr read 4 entries per dependent load.
// ---------------------------------------------------------------------------
__global__ __launch_bounds__(256)
void partition_convw_kernel(const int* __restrict__ src, const int* __restrict__ dst,
                            int* __restrict__ bcursor, int* __restrict__ bpk,
                            const float* __restrict__ W1, const float* __restrict__ W2,
                            __half* __restrict__ Wt1, __half* __restrict__ Wt2) {
    if (blockIdx.x >= NPART) {
        int idx = (blockIdx.x - NPART) * 256 + threadIdx.x;
        if (idx < 128 * 128) {
            int k = idx / 128, j = idx % 128;
            Wt1[(long)j * 128 + k] = __float2half(W1[idx]);
        } else {
            int i = idx - 128 * 128;
            if (i < 128 * 64) {
                int k = i / 64, j = i % 64;
                Wt2[(long)j * 128 + k] = __float2half(W2[i]);
            }
        }
        return;
    }
    constexpr int EPT = PART_CHUNK / 256;   // 16 edges per thread
    __shared__ int hist[NBKT];
    for (int i = threadIdx.x; i < NBKT; i += 256) hist[i] = 0;
    __syncthreads();
    int e0 = blockIdx.x * PART_CHUNK;
    int sv[EPT], dv[EPT];
#pragma unroll
    for (int j = 0; j < EPT; ++j) {
        int e = e0 + j * 256 + threadIdx.x;
        bool ok = e < N_EDGES;
        dv[j] = ok ? dst[e] : -1;
        sv[j] = ok ? src[e] : 0;
    }
#pragma unroll
    for (int j = 0; j < EPT; ++j)
        if (dv[j] >= 0) atomicAdd(&hist[dv[j] >> 8], 1);
    __syncthreads();
    // reserve a contiguous range per (block, bucket): one global atomic each
    for (int i = threadIdx.x; i < NBKT; i += 256) {
        int c = hist[i];
        if (c) {
            int r = atomicAdd(&bcursor[i * BCSTRIDE], c);
            hist[i] = i * BCAP + (r < BCAP ? r : BCAP);
        }
    }
    __syncthreads();
#pragma unroll
    for (int j = 0; j < EPT; ++j) {
        if (dv[j] >= 0) {
            int bkt = dv[j] >> 8;
            int pos = atomicAdd(&hist[bkt], 1);
            if (pos < (bkt + 1) * BCAP)       // overflow guard (never fires)
                bpk[pos] = ((dv[j] & 255) << 24) | sv[j];
        }
    }
}

// ---------------------------------------------------------------------------
// Merged dispatch: blocks [0, NBKT) run CSR phase 2 (localcsr); blocks
// [NBKT, NBKT+GEMM1_BLOCKS) run the layer-1 GEMM.
// R27: explicit LDS union (16384B total, was 19456 with both branches'
// statics summed) + int4 packed loads = 4 entries per dependent load
// (chain 8 -> 4 iterations/pass).
// ---------------------------------------------------------------------------
__global__ __launch_bounds__(256)
void localcsr_gemm1_kernel(const int* __restrict__ bcursor,
                           const int* __restrict__ bpk,
                           int* __restrict__ row_start, int* __restrict__ row_end,
                           int* __restrict__ eidx,
                           const float* __restrict__ x, const __half* __restrict__ Wt1,
                           __half* __restrict__ C,
                           const float* __restrict__ a_s, const float* __restrict__ a_d,
                           float* __restrict__ s_src, float* __restrict__ s_dst) {
    __shared__ __align__(16) char smem[4 * 16 * 128 * 2];   // 16KB union
    if (blockIdx.x >= NBKT) {
        gemm_body<128, D1, true>(blockIdx.x - NBKT, x, Wt1, C,
                                 a_s, a_d, s_src, s_dst, N_NODES, (__half*)smem);
        return;
    }
    // ---- localcsr body (R19-verified; R27 int4 x 4-entry loads) ----
    int* cnt = (int*)smem;            // 256
    int* sh  = cnt + 256;             // 256
    int* cur = sh + 256;              // 256
    int b = blockIdx.x;
    int tid = threadIdx.x;
    int n0 = b << 8;
    int m0 = b * BCAP;                // multiple of 4 -> int4-aligned
    int count = bcursor[b * BCSTRIDE];
    int m1c = (count < BCAP ? count : BCAP);   // entries in this bucket
    int base4 = m1c & ~3;
    const int* bp = bpk + m0;
    cnt[tid] = 0;
    __syncthreads();
    for (int k = tid * 4; k + 3 < m1c; k += 1024) {
        int4 pp = *(const int4*)(bp + k);      // 4 packed entries per load
        atomicAdd(&cnt[(unsigned)pp.x >> 24], 1);
        atomicAdd(&cnt[(unsigned)pp.y >> 24], 1);
        atomicAdd(&cnt[(unsigned)pp.z >> 24], 1);
        atomicAdd(&cnt[(unsigned)pp.w >> 24], 1);
    }
    if (tid == 0)
        for (int k = base4; k < m1c; ++k)
            atomicAdd(&cnt[(unsigned)bp[k] >> 24], 1);
    __syncthreads();
    int c = cnt[tid];
    sh[tid] = c;
    __syncthreads();
    int run = c;
    for (int off = 1; off < 256; off <<= 1) {
        int add = (tid >= off) ? sh[tid - off] : 0;
        __syncthreads();
        run += add;
        sh[tid] = run;
        __syncthreads();
    }
    int excl = run - c;
    cur[tid] = m0 + excl;
    if (n0 + tid < N_NODES) {
        row_start[n0 + tid] = m0 + excl;
        row_end[n0 + tid]   = m0 + excl + c;
    }
    __syncthreads();
    for (int k = tid * 4; k + 3 < m1c; k += 1024) {
        int4 pp = *(const int4*)(bp + k);
        int p0 = atomicAdd(&cur[(unsigned)pp.x >> 24], 1); eidx[p0] = pp.x & 0xFFFFFF;
        int p1 = atomicAdd(&cur[(unsigned)pp.y >> 24], 1); eidx[p1] = pp.y & 0xFFFFFF;
        int p2 = atomicAdd(&cur[(unsigned)pp.z >> 24], 1); eidx[p2] = pp.z & 0xFFFFFF;
        int p3 = atomicAdd(&cur[(unsigned)pp.w >> 24], 1); eidx[p3] = pp.w & 0xFFFFFF;
    }
    if (tid == 0) {
        for (int k = base4; k < m1c; ++k) {
            int pp = bp[k];
            int pos = atomicAdd(&cur[(unsigned)pp >> 24], 1);
            eidx[pos] = pp & 0xFFFFFF;
        }
    }
}

// ---------------------------------------------------------------------------
// Standalone layer-2 GEMM (reads fp16 h1out; scores fused via DPP).
// ---------------------------------------------------------------------------
__global__ __launch_bounds__(256)
void gemm2_kernel(const __half* __restrict__ A, const __half* __restrict__ Bt,
                  __half* __restrict__ C,
                  const float* __restrict__ a_s, const float* __restrict__ a_d,
                  float* __restrict__ s_src, float* __restrict__ s_dst) {
    __shared__ __align__(16) __half stg[4 * 16 * 64];
    gemm_body<64, D2, false>(blockIdx.x, A, Bt, C, a_s, a_d, s_src, s_dst,
                             N_NODES, stg);
}

// ---------------------------------------------------------------------------
// Wave-per-node aggregation (R23 form, best measured: readlane for
// wave-uniform si, scalar gather base). At its wall — 7 independent levers
// (bytes/MLP/VALU/SALU/VMEM-count/layout/split) leave it pinned at ~80us.
// ---------------------------------------------------------------------------
template<int D, bool RELU, typename OT>
__global__ __launch_bounds__(256)
void aggregate_wave_kernel(const int* __restrict__ rs, const int* __restrict__ re,
                           const int* __restrict__ eidx,
                           const __half* __restrict__ h,
                           const float* __restrict__ ssrc, const float* __restrict__ sdst,
                           const float* __restrict__ bias, OT* __restrict__ out) {
    constexpr int F = HEADS * D;       // 128 or 64
    constexpr int EPL = F / 64;        // elements per lane: 2 or 1
    int lane = threadIdx.x & 63;
    int node = blockIdx.x * 4 + (threadIdx.x >> 6);
    node = __builtin_amdgcn_readfirstlane(node);
    if (node >= N_NODES) return;
    int hd = lane >> 3;                // head owning this lane's slice
    int esl = lane & 7;                // edge slot this lane scores

    float sdv = sdst[node * HEADS + hd];
    float sc0 = ssrc[node * HEADS + hd] + sdv;
    float w0 = __expf(sc0 > 0.f ? sc0 : NEG_SLOPE * sc0);
    float wsum = w0;

    float accx, accy = 0.f;
    if constexpr (EPL == 2) {
        float2 v = __half22float2(*(const __half2*)(h + (long)node * F + lane * 2));
        accx = w0 * v.x; accy = w0 * v.y;
    } else {
        accx = w0 * __half2float(h[(long)node * F + lane]);
    }

    int e0 = rs[node], e1 = re[node];
    int e1m1 = e1 - 1;

    for (int e = e0; e < e1; e += 8) {
        int idx = e + esl;
        int ci = idx < e1m1 ? idx : e1m1;          // clamp: address stays valid
        int s_mine = eidx[ci];                     // same 8 values in every group
        float sc = ssrc[s_mine * HEADS + hd] + sdv;
        float w_mine = __expf(sc > 0.f ? sc : NEG_SLOPE * sc);
        w_mine = (idx < e1) ? w_mine : 0.f;        // kill tail slots

        int grp = lane & 56;                       // base lane of my head row
#pragma unroll
        for (int i = 0; i < 8; ++i) {
            // si is wave-uniform (slot i identical across groups): SGPR via
            // readlane; gather becomes scalar-base + lane-offset.
            int si = (int)__builtin_amdgcn_readlane((unsigned)s_mine, i);
            float wi = __shfl(w_mine, grp + i, 64);
            wsum += wi;
            if constexpr (EPL == 2) {
                const __half2* hp = (const __half2*)(h + (long)si * F) + lane;
                float2 v = __half22float2(*hp);
                accx = fmaf(wi, v.x, accx);
                accy = fmaf(wi, v.y, accy);
            } else {
                accx = fmaf(wi, __half2float(h[(long)si * F + lane]), accx);
            }
        }
    }

    float inv = 1.f / (wsum + 1e-16f);
    if constexpr (EPL == 2) {
        float2 b = *(const float2*)(bias + lane * 2);
        float ox = accx * inv + b.x;
        float oy = accy * inv + b.y;
        if (RELU) { ox = fmaxf(ox, 0.f); oy = fmaxf(oy, 0.f); }
        if constexpr (sizeof(OT) == 2) {
            *(__half2*)((__half*)out + (long)node * F + lane * 2) = __floats2half2_rn(ox, oy);
        } else {
            *(float2*)((float*)out + (long)node * F + lane * 2) = make_float2(ox, oy);
        }
    } else {
        float o = accx * inv + bias[lane];
        if (RELU) o = fmaxf(o, 0.f);
        if constexpr (sizeof(OT) == 2) {
            ((__half*)out)[(long)node * F + lane] = __float2half(o);
        } else {
            ((float*)out)[(long)node * F + lane] = o;
        }
    }
}

extern "C" void kernel_launch(void* const* d_in, const int* in_sizes, int n_in,
                              void* d_out, int out_size, void* d_ws, size_t ws_size,
                              hipStream_t stream) {
    const float* x   = (const float*)d_in[0];
    const int*   ei  = (const int*)d_in[1];      // [2, N_EDGES] row-major
    const float* W1  = (const float*)d_in[2];
    const float* a1s = (const float*)d_in[3];
    const float* a1d = (const float*)d_in[4];
    const float* b1  = (const float*)d_in[5];
    const float* W2  = (const float*)d_in[6];
    const float* a2s = (const float*)d_in[7];
    const float* a2d = (const float*)d_in[8];
    const float* b2  = (const float*)d_in[9];
    float* out = (float*)d_out;

    const int* src = ei;
    const int* dst = ei + N_EDGES;

    // ---- workspace layout (R19/R27) ----
    float* ws = (float*)d_ws;
    float* bufA = ws;                                  // 51.2MB slot:
                                                       //   [0..25.6MB) h1/h2 fp16
                                                       //   [32MB..41.6MB) padded eidx
    float* bufB = bufA + (size_t)N_NODES * 128;        // 51.2MB slot, time-shared:
                                                       //   packed bpk (9.6MB) -> h1out
    float* ssrc = bufB + (size_t)N_NODES * 128;        // N*8
    float* sdst = ssrc + (size_t)N_NODES * HEADS;      // N*8
    int* counts    = (int*)(sdst + (size_t)N_NODES * HEADS);  // N ints (carved below)
    int* row_start = counts + N_NODES;                 // N+1
    int* row_end   = row_start + N_NODES + 1;          // N

    int* bcursor = counts + 1024;            // NBKT*BCSTRIDE ints (line-padded)
    __half* Wt1  = (__half*)(counts + 1024 + NBKT * BCSTRIDE);          // 8192 ints
    __half* Wt2  = (__half*)(counts + 1024 + NBKT * BCSTRIDE + 8192);   // 4096 ints
    int* bpk      = (int*)bufB;              // NBKT*BCAP*4B = 9.6MB; dead before h1out
    __half* h1out = (__half*)bufB;           // N*128 fp16; written by agg L1
    int* eidx = (int*)((char*)bufA + (size_t)32 * 1024 * 1024);  // NBKT*BCAP ints = 9.6MB

    __half* hbuf = (__half*)bufA;

    // ---- 5 dispatches + 1 memset ----
    hipMemsetAsync(bcursor, 0, (size_t)NBKT * BCSTRIDE * sizeof(int), stream);
    // merged: partition (391 blocks) || weight convert (96 blocks)
    partition_convw_kernel<<<NPART + NCONV, 256, 0, stream>>>(
        src, dst, bcursor, bpk, W1, W2, Wt1, Wt2);
    // merged: CSR phase 2 (391 blocks) || layer-1 GEMM (1563 blocks)
    localcsr_gemm1_kernel<<<NBKT + GEMM1_BLOCKS, 256, 0, stream>>>(
        bcursor, bpk, row_start, row_end, eidx,
        x, Wt1, hbuf, a1s, a1d, ssrc, sdst);
    aggregate_wave_kernel<D1, true, __half><<<(N_NODES + 3) / 4, 256, 0, stream>>>(
        row_start, row_end, eidx, hbuf, ssrc, sdst, b1, h1out);
    gemm2_kernel<<<GEMM1_BLOCKS, 256, 0, stream>>>(
        h1out, Wt2, hbuf, a2s, a2d, ssrc, sdst);
    aggregate_wave_kernel<D2, false, float><<<(N_NODES + 3) / 4, 256, 0, stream>>>(
        row_start, row_end, eidx, hbuf, ssrc, sdst, b2, out);
}

// Round 18
// 316.986 us; speedup vs baseline: 1.0980x; 1.0120x over previous
//
#include <hip/hip_runtime.h>
#include <hip/hip_fp16.h>
#include <math.h>

#define N_NODES 100000
#define N_EDGES 1600000
#define IN_DIM 128
#define HEADS 8
#define D1 16
#define D2 8
#define NEG_SLOPE 0.2f

#define NBKT ((N_NODES + 255) / 256)      // 391 buckets of 256 dst nodes
#define PART_CHUNK 4096                   // R16 lesson: bigger chunks -> occupancy collapse
#define NPART ((N_EDGES + PART_CHUNK - 1) / PART_CHUNK)   // 391 partition blocks
#define NCONV ((128 * 128 + 128 * 64 + 255) / 256)        // 96 convert blocks
#define BCAP 6144                         // R19: fixed bucket capacity = mean 4096 + 32 sigma
#define BCSTRIDE 32                       // R21: one 128B line per bucket cursor (kept; free)
#define GEMM1_BLOCKS ((N_NODES + 63) / 64)

typedef _Float16 f16x8 __attribute__((ext_vector_type(8)));
typedef float    f32x4 __attribute__((ext_vector_type(4)));

// 16-byte pack of 8 halves.
struct __align__(16) half8 { __half2 a, b, c, d; };

__device__ __forceinline__ f16x8 load_cvt8(const float* p) {
    float4 v0 = *(const float4*)p, v1 = *(const float4*)(p + 4);
    f16x8 r;
    r[0] = (_Float16)v0.x; r[1] = (_Float16)v0.y;
    r[2] = (_Float16)v0.z; r[3] = (_Float16)v0.w;
    r[4] = (_Float16)v1.x; r[5] = (_Float16)v1.y;
    r[6] = (_Float16)v1.z; r[7] = (_Float16)v1.w;
    return r;
}

// DPP row_shr:N add (VALU only). bound_ctrl=true: OOB reads 0.
// row_shr:N: lane i reads lane i-N — accumulation flows toward HIGHER lanes;
// after shr 8,4,2,1 the 16-lane row sum is in lane 15 (R17 bug: stored from
// lane 0). 8-lane group sums land in lanes 7 and 15.
template<int CTRL>
__device__ __forceinline__ float dpp_add(float x) {
    int y = __builtin_amdgcn_update_dpp(0, __builtin_bit_cast(int, x),
                                        CTRL, 0xF, 0xF, true);
    return x + __builtin_bit_cast(float, y);
}

// ---------------------------------------------------------------------------
// MFMA GEMM body + fused score epilogue (DPP reduce, R18-verified; R22 LDS
// restage for wide coalesced h-stores; R27 hoisted staging tile).
// Fragment pattern (guide m90/m92, HW-verified):
//   A-frag: lane reads A[row0+(lane&15)][ks..ks+8), ks=(lane>>4)*8 per 32-k step
//   B-frag: same from Bt rows (Bt = W^T)
//   C/D  : row=(lane>>4)*4+r, col=j*16+(lane&15)
// Score fusion: col j*16+lr == head*D+d flat for BOTH layers.
// XF32: layer-1 reads x fp32, converts in-register (RN, == old convert_x).
// ---------------------------------------------------------------------------
template<int OUTC, int D, bool XF32>
__device__ __forceinline__ void gemm_body(int gb, const void* __restrict__ Ain,
                                          const __half* __restrict__ Bt,
                                          __half* __restrict__ C,
                                          const float* __restrict__ a_s,
                                          const float* __restrict__ a_d,
                                          float* __restrict__ s_src,
                                          float* __restrict__ s_dst,
                                          int n_rows, __half* stg) {
    constexpr int K = 128;
    constexpr int NT = OUTC / 16;      // col tiles: 8 (L1) or 4 (L2)
    int wid  = threadIdx.x >> 6;
    int lane = threadIdx.x & 63;
    int row0 = gb * 64 + wid * 16;
    int lr   = lane & 15;              // M-row within tile (A) / N-col (B)
    int ks   = (lane >> 4) * 8;        // k-slice base within 32-k subtile

    int arow = row0 + lr;
    arow = arow < n_rows ? arow : n_rows - 1;   // clamp tail, stores guarded

    f16x8 a0, a1, a2, a3;
    if constexpr (XF32) {
        const float* ap = (const float*)Ain + (long)arow * K + ks;
        a0 = load_cvt8(ap);
        a1 = load_cvt8(ap + 32);
        a2 = load_cvt8(ap + 64);
        a3 = load_cvt8(ap + 96);
    } else {
        const __half* ap = (const __half*)Ain + (long)arow * K + ks;
        a0 = *(const f16x8*)(ap);
        a1 = *(const f16x8*)(ap + 32);
        a2 = *(const f16x8*)(ap + 64);
        a3 = *(const f16x8*)(ap + 96);
    }

    f32x4 acc[NT];
#pragma unroll
    for (int j = 0; j < NT; ++j) acc[j] = (f32x4)(0.f);

#pragma unroll
    for (int j = 0; j < NT; ++j) {
        const __half* bp = Bt + (long)(j * 16 + lr) * K + ks;
        f16x8 b0 = *(const f16x8*)(bp);
        f16x8 b1 = *(const f16x8*)(bp + 32);
        f16x8 b2 = *(const f16x8*)(bp + 64);
        f16x8 b3 = *(const f16x8*)(bp + 96);
        acc[j] = __builtin_amdgcn_mfma_f32_16x16x32_f16(a0, b0, acc[j], 0, 0, 0);
        acc[j] = __builtin_amdgcn_mfma_f32_16x16x32_f16(a1, b1, acc[j], 0, 0, 0);
        acc[j] = __builtin_amdgcn_mfma_f32_16x16x32_f16(a2, b2, acc[j], 0, 0, 0);
        acc[j] = __builtin_amdgcn_mfma_f32_16x16x32_f16(a3, b3, acc[j], 0, 0, 0);
    }

    // per-lane attention-vector slice (flat index j*16+lr works for both D)
    float asv[NT], adv[NT];
#pragma unroll
    for (int j = 0; j < NT; ++j) {
        asv[j] = a_s[j * 16 + lr];
        adv[j] = a_d[j * 16 + lr];
    }

    __half* sp_ = stg + wid * 16 * OUTC;   // per-wave staging region

    int rbase4 = (lane >> 4) * 4;      // local row base within the wave tile
#pragma unroll
    for (int r = 0; r < 4; ++r) {
        int lrow = rbase4 + r;

        // ---- h staged to LDS (replaces scattered 2B global stores) ----
#pragma unroll
        for (int j = 0; j < NT; ++j)
            sp_[lrow * OUTC + j * 16 + lr] = __float2half(acc[j][r]);

        int rr = row0 + lrow;
        bool valid = rr < n_rows;

        // ---- fused scores: DPP row reduction (sums -> high lanes) ----
        float ps[NT], pd[NT];
#pragma unroll
        for (int j = 0; j < NT; ++j) {
            ps[j] = acc[j][r] * asv[j];
            pd[j] = acc[j][r] * adv[j];
        }
        if constexpr (D == 16) {
#pragma unroll
            for (int j = 0; j < NT; ++j) {
                ps[j] = dpp_add<0x118>(ps[j]); ps[j] = dpp_add<0x114>(ps[j]);
                ps[j] = dpp_add<0x112>(ps[j]); ps[j] = dpp_add<0x111>(ps[j]);
                pd[j] = dpp_add<0x118>(pd[j]); pd[j] = dpp_add<0x114>(pd[j]);
                pd[j] = dpp_add<0x112>(pd[j]); pd[j] = dpp_add<0x111>(pd[j]);
            }
            // lane 15 of each 16-row holds the row sum -> 2x 32B stores
            if (valid && lr == 15) {
                float* sp = s_src + rr * 8;
                float* dp = s_dst + rr * 8;
                *(float4*)(sp)     = make_float4(ps[0], ps[1], ps[2], ps[3]);
                *(float4*)(sp + 4) = make_float4(ps[4], ps[5], ps[6], ps[7]);
                *(float4*)(dp)     = make_float4(pd[0], pd[1], pd[2], pd[3]);
                *(float4*)(dp + 4) = make_float4(pd[4], pd[5], pd[6], pd[7]);
            }
        } else {
#pragma unroll
            for (int j = 0; j < NT; ++j) {
                ps[j] = dpp_add<0x114>(ps[j]); ps[j] = dpp_add<0x112>(ps[j]);
                ps[j] = dpp_add<0x111>(ps[j]);
                pd[j] = dpp_add<0x114>(pd[j]); pd[j] = dpp_add<0x112>(pd[j]);
                pd[j] = dpp_add<0x111>(pd[j]);
            }
            // lane 7: sum of lanes 0-7 (head 2j); lane 15: lanes 8-15 (head 2j+1)
            if (valid && lr == 7) {
#pragma unroll
                for (int j = 0; j < NT; ++j) {
                    s_src[rr * 8 + 2 * j] = ps[j];
                    s_dst[rr * 8 + 2 * j] = pd[j];
                }
            }
            if (valid && lr == 15) {
#pragma unroll
                for (int j = 0; j < NT; ++j) {
                    s_src[rr * 8 + 2 * j + 1] = ps[j];
                    s_dst[rr * 8 + 2 * j + 1] = pd[j];
                }
            }
        }
    }

    // ---- wide h store: the wave's 16xOUTC tile is contiguous in C ----
    constexpr int CPR = OUTC / 8;      // 16B chunks per row
    constexpr int CPL = 2 * OUTC / 64; // chunks per lane: 4 (L1) / 2 (L2)
#pragma unroll
    for (int t = 0; t < CPL; ++t) {
        int c = t * 64 + lane;         // consecutive lanes -> consecutive chunks
        int row = c / CPR;
        if (row0 + row < n_rows) {
            half8 v = *(half8*)(sp_ + c * 8);
            *(half8*)(C + (long)row0 * OUTC + c * 8) = v;
        }
    }
}

// ---------------------------------------------------------------------------
// Merged front: partition (NPART blocks) || weight convert (NCONV).
// bpairs packed to ONE int: (local_dst<<24)|src.
// ---------------------------------------------------------------------------
__global__ __launch_bounds__(256)
void partition_convw_kernel(const int* __restrict__ src, const int* __restrict__ dst,
                            int* __restrict__ bcursor, int* __restrict__ bpk,
                            const float* __restrict__ W1, const float* __restrict__ W2,
                            __half* __restrict__ Wt1, __half* __restrict__ Wt2) {
    if (blockIdx.x >= NPART) {
        int idx = (blockIdx.x - NPART) * 256 + threadIdx.x;
        if (idx < 128 * 128) {
            int k = idx / 128, j = idx % 128;
            Wt1[(long)j * 128 + k] = __float2half(W1[idx]);
        } else {
            int i = idx - 128 * 128;
            if (i < 128 * 64) {
                int k = i / 64, j = i % 64;
                Wt2[(long)j * 128 + k] = __float2half(W2[i]);
            }
        }
        return;
    }
    constexpr int EPT = PART_CHUNK / 256;   // 16 edges per thread
    __shared__ int hist[NBKT];
    for (int i = threadIdx.x; i < NBKT; i += 256) hist[i] = 0;
    __syncthreads();
    int e0 = blockIdx.x * PART_CHUNK;
    int sv[EPT], dv[EPT];
#pragma unroll
    for (int j = 0; j < EPT; ++j) {
        int e = e0 + j * 256 + threadIdx.x;
        bool ok = e < N_EDGES;
        dv[j] = ok ? dst[e] : -1;
        sv[j] = ok ? src[e] : 0;
    }
#pragma unroll
    for (int j = 0; j < EPT; ++j)
        if (dv[j] >= 0) atomicAdd(&hist[dv[j] >> 8], 1);
    __syncthreads();
    // reserve a contiguous range per (block, bucket): one global atomic each
    for (int i = threadIdx.x; i < NBKT; i += 256) {
        int c = hist[i];
        if (c) {
            int r = atomicAdd(&bcursor[i * BCSTRIDE], c);
            hist[i] = i * BCAP + (r < BCAP ? r : BCAP);
        }
    }
    __syncthreads();
#pragma unroll
    for (int j = 0; j < EPT; ++j) {
        if (dv[j] >= 0) {
            int bkt = dv[j] >> 8;
            int pos = atomicAdd(&hist[bkt], 1);
            if (pos < (bkt + 1) * BCAP)       // overflow guard (never fires)
                bpk[pos] = ((dv[j] & 255) << 24) | sv[j];
        }
    }
}

// ---------------------------------------------------------------------------
// Merged dispatch: blocks [0, NBKT) run CSR phase 2 (localcsr); blocks
// [NBKT, NBKT+GEMM1_BLOCKS) run the layer-1 GEMM. 16KB LDS union (R27).
// ---------------------------------------------------------------------------
__global__ __launch_bounds__(256)
void localcsr_gemm1_kernel(const int* __restrict__ bcursor,
                           const int* __restrict__ bpk,
                           int* __restrict__ row_start, int* __restrict__ row_end,
                           int* __restrict__ eidx,
                           const float* __restrict__ x, const __half* __restrict__ Wt1,
                           __half* __restrict__ C,
                           const float* __restrict__ a_s, const float* __restrict__ a_d,
                           float* __restrict__ s_src, float* __restrict__ s_dst) {
    __shared__ __align__(16) char smem[4 * 16 * 128 * 2];   // 16KB union
    if (blockIdx.x >= NBKT) {
        gemm_body<128, D1, true>(blockIdx.x - NBKT, x, Wt1, C,
                                 a_s, a_d, s_src, s_dst, N_NODES, (__half*)smem);
        return;
    }
    // ---- localcsr body (R19-verified; R27 int4 x 4-entry loads) ----
    int* cnt = (int*)smem;            // 256
    int* sh  = cnt + 256;             // 256
    int* cur = sh + 256;              // 256
    int b = blockIdx.x;
    int tid = threadIdx.x;
    int n0 = b << 8;
    int m0 = b * BCAP;                // multiple of 4 -> int4-aligned
    int count = bcursor[b * BCSTRIDE];
    int m1c = (count < BCAP ? count : BCAP);   // entries in this bucket
    int base4 = m1c & ~3;
    const int* bp = bpk + m0;
    cnt[tid] = 0;
    __syncthreads();
    for (int k = tid * 4; k + 3 < m1c; k += 1024) {
        int4 pp = *(const int4*)(bp + k);      // 4 packed entries per load
        atomicAdd(&cnt[(unsigned)pp.x >> 24], 1);
        atomicAdd(&cnt[(unsigned)pp.y >> 24], 1);
        atomicAdd(&cnt[(unsigned)pp.z >> 24], 1);
        atomicAdd(&cnt[(unsigned)pp.w >> 24], 1);
    }
    if (tid == 0)
        for (int k = base4; k < m1c; ++k)
            atomicAdd(&cnt[(unsigned)bp[k] >> 24], 1);
    __syncthreads();
    int c = cnt[tid];
    sh[tid] = c;
    __syncthreads();
    int run = c;
    for (int off = 1; off < 256; off <<= 1) {
        int add = (tid >= off) ? sh[tid - off] : 0;
        __syncthreads();
        run += add;
        sh[tid] = run;
        __syncthreads();
    }
    int excl = run - c;
    cur[tid] = m0 + excl;
    if (n0 + tid < N_NODES) {
        row_start[n0 + tid] = m0 + excl;
        row_end[n0 + tid]   = m0 + excl + c;
    }
    __syncthreads();
    for (int k = tid * 4; k + 3 < m1c; k += 1024) {
        int4 pp = *(const int4*)(bp + k);
        int p0 = atomicAdd(&cur[(unsigned)pp.x >> 24], 1); eidx[p0] = pp.x & 0xFFFFFF;
        int p1 = atomicAdd(&cur[(unsigned)pp.y >> 24], 1); eidx[p1] = pp.y & 0xFFFFFF;
        int p2 = atomicAdd(&cur[(unsigned)pp.z >> 24], 1); eidx[p2] = pp.z & 0xFFFFFF;
        int p3 = atomicAdd(&cur[(unsigned)pp.w >> 24], 1); eidx[p3] = pp.w & 0xFFFFFF;
    }
    if (tid == 0) {
        for (int k = base4; k < m1c; ++k) {
            int pp = bp[k];
            int pos = atomicAdd(&cur[(unsigned)pp >> 24], 1);
            eidx[pos] = pp & 0xFFFFFF;
        }
    }
}

// ---------------------------------------------------------------------------
// Standalone layer-2 GEMM (reads fp16 h1out; scores fused via DPP).
// ---------------------------------------------------------------------------
__global__ __launch_bounds__(256)
void gemm2_kernel(const __half* __restrict__ A, const __half* __restrict__ Bt,
                  __half* __restrict__ C,
                  const float* __restrict__ a_s, const float* __restrict__ a_d,
                  float* __restrict__ s_src, float* __restrict__ s_dst) {
    __shared__ __align__(16) __half stg[4 * 16 * 64];
    gemm_body<64, D2, false>(blockIdx.x, A, Bt, C, a_s, a_d, s_src, s_dst,
                             N_NODES, stg);
}

// ---------------------------------------------------------------------------
// Wave-per-node aggregation.
// R28: 2-DEEP SOFTWARE PIPELINE of the per-group dependent chain.
// Cycle accounting: 100K waves / 1024 SIMDs, 192K cyc -> ~2000 effective
// serial cycles per wave, vs ~450 issue cycles (R23 disproved issue-bound)
// — the residual is the eidx -> ssrc[random] -> exp chain (~1100+ cyc)
// repeated serially per 8-edge group. Skew: at group k issue A=eidx(k+2)
// and B=ssrc(k+1) BEFORE computing C(k); A(k+2) has a full iteration to
// land before B(k+2) needs it; B(k+1)'s latency hides under C(k)'s
// h-gathers. Same values, same accumulation order -> bitwise-identical.
// ---------------------------------------------------------------------------
template<int D, bool RELU, typename OT>
__global__ __launch_bounds__(256)
void aggregate_wave_kernel(const int* __restrict__ rs, const int* __restrict__ re,
                           const int* __restrict__ eidx,
                           const __half* __restrict__ h,
                           const float* __restrict__ ssrc, const float* __restrict__ sdst,
                           const float* __restrict__ bias, OT* __restrict__ out) {
    constexpr int F = HEADS * D;       // 128 or 64
    constexpr int EPL = F / 64;        // elements per lane: 2 or 1
    int lane = threadIdx.x & 63;
    int node = blockIdx.x * 4 + (threadIdx.x >> 6);
    node = __builtin_amdgcn_readfirstlane(node);
    if (node >= N_NODES) return;
    int hd = lane >> 3;                // head owning this lane's slice
    int esl = lane & 7;                // edge slot this lane scores

    float sdv = sdst[node * HEADS + hd];
    float sc0 = ssrc[node * HEADS + hd] + sdv;
    float w0 = __expf(sc0 > 0.f ? sc0 : NEG_SLOPE * sc0);
    float wsum = w0;

    float accx, accy = 0.f;
    if constexpr (EPL == 2) {
        float2 v = __half22float2(*(const __half2*)(h + (long)node * F + lane * 2));
        accx = w0 * v.x; accy = w0 * v.y;
    } else {
        accx = w0 * __half2float(h[(long)node * F + lane]);
    }

    int e0 = rs[node], e1 = re[node];
    int e1m1 = e1 - 1;
    int grp = lane & 56;                           // base lane of my head row

    if (e0 < e1) {
        // ---- pipeline prologue: A(0), A(1) in flight together; B(0) ----
        int i0 = e0 + esl;
        int sA = eidx[i0 < e1m1 ? i0 : e1m1];
        int sB = 0;
        if (e0 + 8 < e1) {
            int i1 = e0 + 8 + esl;
            sB = eidx[i1 < e1m1 ? i1 : e1m1];
        }
        float rawA = ssrc[sA * HEADS + hd];

        for (int e = e0; e < e1; e += 8) {
            bool has1 = e + 8 < e1;
            bool has2 = e + 16 < e1;
            // A(k+2): no dependencies, issues immediately
            int sC = 0;
            if (has2) {
                int i2 = e + 16 + esl;
                sC = eidx[i2 < e1m1 ? i2 : e1m1];
            }
            // B(k+1): depends on sB (loaded a full iteration ago)
            float rawB = 0.f;
            if (has1) rawB = ssrc[sB * HEADS + hd];
            // ---- C(k): weight + gathers from sA/rawA ----
            float sc = rawA + sdv;
            float w_mine = __expf(sc > 0.f ? sc : NEG_SLOPE * sc);
            w_mine = (e + esl < e1) ? w_mine : 0.f;    // kill tail slots
#pragma unroll
            for (int i = 0; i < 8; ++i) {
                int si = (int)__builtin_amdgcn_readlane((unsigned)sA, i);
                float wi = __shfl(w_mine, grp + i, 64);
                wsum += wi;
                if constexpr (EPL == 2) {
                    const __half2* hp = (const __half2*)(h + (long)si * F) + lane;
                    float2 v = __half22float2(*hp);
                    accx = fmaf(wi, v.x, accx);
                    accy = fmaf(wi, v.y, accy);
                } else {
                    accx = fmaf(wi, __half2float(h[(long)si * F + lane]), accx);
                }
            }
            sA = sB; sB = sC; rawA = rawB;
        }
    }

    float inv = 1.f / (wsum + 1e-16f);
    if constexpr (EPL == 2) {
        float2 b = *(const float2*)(bias + lane * 2);
        float ox = accx * inv + b.x;
        float oy = accy * inv + b.y;
        if (RELU) { ox = fmaxf(ox, 0.f); oy = fmaxf(oy, 0.f); }
        if constexpr (sizeof(OT) == 2) {
            *(__half2*)((__half*)out + (long)node * F + lane * 2) = __floats2half2_rn(ox, oy);
        } else {
            *(float2*)((float*)out + (long)node * F + lane * 2) = make_float2(ox, oy);
        }
    } else {
        float o = accx * inv + bias[lane];
        if (RELU) o = fmaxf(o, 0.f);
        if constexpr (sizeof(OT) == 2) {
            ((__half*)out)[(long)node * F + lane] = __float2half(o);
        } else {
            ((float*)out)[(long)node * F + lane] = o;
        }
    }
}

extern "C" void kernel_launch(void* const* d_in, const int* in_sizes, int n_in,
                              void* d_out, int out_size, void* d_ws, size_t ws_size,
                              hipStream_t stream) {
    const float* x   = (const float*)d_in[0];
    const int*   ei  = (const int*)d_in[1];      // [2, N_EDGES] row-major
    const float* W1  = (const float*)d_in[2];
    const float* a1s = (const float*)d_in[3];
    const float* a1d = (const float*)d_in[4];
    const float* b1  = (const float*)d_in[5];
    const float* W2  = (const float*)d_in[6];
    const float* a2s = (const float*)d_in[7];
    const float* a2d = (const float*)d_in[8];
    const float* b2  = (const float*)d_in[9];
    float* out = (float*)d_out;

    const int* src = ei;
    const int* dst = ei + N_EDGES;

    // ---- workspace layout (R19/R27) ----
    float* ws = (float*)d_ws;
    float* bufA = ws;                                  // 51.2MB slot:
                                                       //   [0..25.6MB) h1/h2 fp16
                                                       //   [32MB..41.6MB) padded eidx
    float* bufB = bufA + (size_t)N_NODES * 128;        // 51.2MB slot, time-shared:
                                                       //   packed bpk (9.6MB) -> h1out
    float* ssrc = bufB + (size_t)N_NODES * 128;        // N*8
    float* sdst = ssrc + (size_t)N_NODES * HEADS;      // N*8
    int* counts    = (int*)(sdst + (size_t)N_NODES * HEADS);  // N ints (carved below)
    int* row_start = counts + N_NODES;                 // N+1
    int* row_end   = row_start + N_NODES + 1;          // N

    int* bcursor = counts + 1024;            // NBKT*BCSTRIDE ints (line-padded)
    __half* Wt1  = (__half*)(counts + 1024 + NBKT * BCSTRIDE);          // 8192 ints
    __half* Wt2  = (__half*)(counts + 1024 + NBKT * BCSTRIDE + 8192);   // 4096 ints
    int* bpk      = (int*)bufB;              // NBKT*BCAP*4B = 9.6MB; dead before h1out
    __half* h1out = (__half*)bufB;           // N*128 fp16; written by agg L1
    int* eidx = (int*)((char*)bufA + (size_t)32 * 1024 * 1024);  // NBKT*BCAP ints = 9.6MB

    __half* hbuf = (__half*)bufA;

    // ---- 5 dispatches + 1 memset ----
    hipMemsetAsync(bcursor, 0, (size_t)NBKT * BCSTRIDE * sizeof(int), stream);
    // merged: partition (391 blocks) || weight convert (96 blocks)
    partition_convw_kernel<<<NPART + NCONV, 256, 0, stream>>>(
        src, dst, bcursor, bpk, W1, W2, Wt1, Wt2);
    // merged: CSR phase 2 (391 blocks) || layer-1 GEMM (1563 blocks)
    localcsr_gemm1_kernel<<<NBKT + GEMM1_BLOCKS, 256, 0, stream>>>(
        bcursor, bpk, row_start, row_end, eidx,
        x, Wt1, hbuf, a1s, a1d, ssrc, sdst);
    aggregate_wave_kernel<D1, true, __half><<<(N_NODES + 3) / 4, 256, 0, stream>>>(
        row_start, row_end, eidx, hbuf, ssrc, sdst, b1, h1out);
    gemm2_kernel<<<GEMM1_BLOCKS, 256, 0, stream>>>(
        h1out, Wt2, hbuf, a2s, a2d, ssrc, sdst);
    aggregate_wave_kernel<D2, false, float><<<(N_NODES + 3) / 4, 256, 0, stream>>>(
        row_start, row_end, eidx, hbuf, ssrc, sdst, b2, out);
}